// Round 7
// baseline (419.082 us; speedup 1.0000x reference)
//
#include <hip/hip_runtime.h>
#include <hip/hip_bf16.h>
#include <stdint.h>

// Problem constants
#define B_N   2048
#define XW    128      // x row width (real 64 | meta 64)
#define KDIM  512      // W_out column count (= H)
#define NROWS_W   66112
#define NROWS_PAD 66560   // padded bf16-W rows

typedef __bf16 v8bf  __attribute__((ext_vector_type(8)));
typedef float  f32x4 __attribute__((ext_vector_type(4)));

__device__ __forceinline__ unsigned short f2bf(float f) {
    uint32_t u = __float_as_uint(f);
    u += 0x7FFF + ((u >> 16) & 1);          // round-to-nearest-even
    return (unsigned short)(u >> 16);
}
__device__ __forceinline__ float elu1(float v) {
    return v > 0.0f ? v : expm1f(v);
}

// ---------------- K1: h = elu(meta @ W_in^T + b_in), stored bf16 ----------------
__global__ void k_h(const float* __restrict__ x, const float* __restrict__ W_in,
                    const float* __restrict__ b_in, unsigned short* __restrict__ hb) {
    int idx = blockIdx.x * 256 + threadIdx.x;      // b*512 + j
    int b = idx >> 9, j = idx & 511;
    const float4* xm = (const float4*)(x + (size_t)b * XW + 64);
    const float4* wr = (const float4*)(W_in + (size_t)j * 64);
    float acc = 0.f;
#pragma unroll
    for (int q = 0; q < 16; ++q) {
        float4 a = xm[q], w = wr[q];
        acc += a.x * w.x + a.y * w.y + a.z * w.z + a.w * w.w;
    }
    acc = elu1(acc + b_in[j]);
    hb[idx] = f2bf(acc);
}

// ---------------- K-conv: W_out f32 -> bf16 (padded rows zeroed) ---------------
__global__ void k_conv(const float* __restrict__ Wf, unsigned short* __restrict__ Wb) {
    size_t c = (size_t)blockIdx.x * 256 + threadIdx.x;  // 8-elem chunk id
    size_t row = c >> 6; int kk = (int)(c & 63);
    union { uint4 v; unsigned short u[8]; } o;
    o.v = (uint4){0, 0, 0, 0};
    if (row < NROWS_W) {
        const float* wp = Wf + row * KDIM + kk * 8;
        float4 w0 = *(const float4*)wp, w1 = *(const float4*)(wp + 4);
        o.u[0] = f2bf(w0.x); o.u[1] = f2bf(w0.y); o.u[2] = f2bf(w0.z); o.u[3] = f2bf(w0.w);
        o.u[4] = f2bf(w1.x); o.u[5] = f2bf(w1.y); o.u[6] = f2bf(w1.z); o.u[7] = f2bf(w1.w);
    }
    *(uint4*)(Wb + c * 8) = o.v;
}

// ---------------- K-init-ypre: ypre = b_out[32768+hh] + sum_i real_i*b_out[i*512+hh]
__global__ void k_init_ypre(const float* __restrict__ x, const float* __restrict__ b_out,
                            float* __restrict__ ypre) {
    int idx = blockIdx.x * 256 + threadIdx.x;   // b*512 + hh
    int b = idx >> 9, hh = idx & 511;
    float acc = b_out[32768 + hh];
    const float* xr = x + (size_t)b * XW;       // real part
#pragma unroll 8
    for (int i = 0; i < 64; ++i)
        acc += xr[i] * b_out[i * 512 + hh];
    ypre[idx] = acc;
}

// ---------------- K-y: yv = elu(ypre)  (elu computed ONCE per element) ---------
__global__ void k_y(const float* __restrict__ ypre, float* __restrict__ yv) {
    int idx = blockIdx.x * 256 + threadIdx.x;
    yv[idx] = elu1(ypre[idx]);
}

// ---------------- K-init-out: out = b_out[66048+o] + sum_hh yv*b_out[33280+hh*64+o]
__global__ void k_init_out(const float* __restrict__ yv, const float* __restrict__ b_out,
                           float* __restrict__ out) {
    int idx = blockIdx.x * 256 + threadIdx.x;   // b*64 + o
    int b = idx >> 6, o = idx & 63;
    float acc = b_out[66048 + o];
    const float* yr = yv + (size_t)b * 512;
#pragma unroll 4
    for (int hh = 0; hh < 512; ++hh)
        acc += yr[hh] * b_out[33280 + hh * 64 + o];
    out[idx] = acc;
}

// ---------------- panel GEMM: barrier-free, B direct global->VGPR --------------
// P[b,c] = sum_k h[b,k] * W[panelrow(p)+c, k]   (bf16 MFMA, K-quarters of 128)
// outAcc[b, outcol] += s(b, grp) * P            (f32 epilogue per (p,kq))
// Block: 128 rows x 128 panel-cols, 256 thr (4 waves 2x2, wave-tile 64x64).
// A (=h) fragments in regs per kq. B fragments loaded straight from global
// (Wb is L2/L3-resident; lanes {l,l+16,l+32,l+48} of one load read 64
// consecutive bytes of a row -> full-cache-line coalescing). NO barriers in
// the main loop -> free-running waves hide each other's latency.
template<int MODE>
__global__ __launch_bounds__(256, 2)
void k_pgemm(const unsigned short* __restrict__ hb,
             const unsigned short* __restrict__ Wb,
             const float* __restrict__ scaleSrc,
             float* __restrict__ outAcc) {
    constexpr int NP   = MODE ? 129 : 130;
    constexpr int OUTW = MODE ? 64 : 512;
    constexpr int SCW  = MODE ? 18 : 9;

    __shared__ float sc[SCW * 128];           // read-only after init barrier

    // XCD-pinned map: 512 blocks; XCD (lid&7) hosts 4 (split,nh) combos so its
    // B working set is ~4 x 1.04 MB, L2-sized. hb (2 MB) stays hot via reuse.
    const int lid = blockIdx.x;               // [0,512)
    const int c8 = lid & 7, u = (lid >> 3) & 15, v = lid >> 7;
    const int combo = c8 + 8 * v;             // 0..31
    const int s  = combo >> 1, nh = combo & 1;
    const int m0 = u * 128;

    const int pBeg = (NP * s) >> 4;
    const int pEnd = (NP * (s + 1)) >> 4;
    const int halfS = (MODE == 0 && pBeg >= 65) ? 1 : 0;   // uniform per split
    const int iBeg  = pBeg - halfS * 65;

    const int tid = threadIdx.x;
    const int wid = tid >> 6, l = tid & 63;
    const int lr = l & 15, lg = l >> 4;
    const int wm = wid >> 1, wn = wid & 1;                 // wave grid 2x2

    // ---- stage scales into LDS ----
    for (int c = tid; c < SCW * 128; c += 256) {
        int jj = c >> 7, row = c & 127;
        float vs = 1.0f;
        if (MODE == 0) {
            int i = iBeg + jj;
            if (i < 64) vs = scaleSrc[(size_t)(m0 + row) * XW + i];
        } else {
            int g = (pBeg + (jj >> 1)) * 4 + nh * 2 + (jj & 1);
            if (g < 512) vs = scaleSrc[(size_t)(m0 + row) * KDIM + g];  // yv (elu'd)
        }
        sc[c] = vs;
    }
    __syncthreads();                           // the ONLY barrier

    f32x4 accP[4][4], accO[4][4];
#pragma unroll
    for (int mi = 0; mi < 4; ++mi)
#pragma unroll
        for (int ni = 0; ni < 4; ++ni) {
            accP[mi][ni] = (f32x4){0.f, 0.f, 0.f, 0.f};
            accO[mi][ni] = (f32x4){0.f, 0.f, 0.f, 0.f};
        }

    for (int kq = 0; kq < 4; ++kq) {
        // ---- A fragments for this kq -> registers (L2-hot) ----
        const unsigned short* abase = hb + (size_t)(m0 + wm * 64 + lr) * KDIM
                                    + kq * 128 + lg * 8;
        v8bf areg[4][4];                                  // [mi][ks], static idx only
#pragma unroll
        for (int mi = 0; mi < 4; ++mi)
#pragma unroll
            for (int kk2 = 0; kk2 < 4; ++kk2)
                areg[mi][kk2] = *(const v8bf*)(abase + mi * 16 * KDIM + kk2 * 32);

        for (int p = pBeg; p < pEnd; ++p) {
            const int wrow = MODE ? (33280 + p * 256 + nh * 128)
                                  : ((p - halfS * 65) * 512 + halfS * 256 + nh * 128);
            const unsigned short* bbase = Wb + (size_t)(wrow + wn * 64 + lr) * KDIM
                                        + kq * 128 + lg * 8;
            // ---- issue all 16 B-frag loads (independent; compiler counts vmcnt)
            v8bf b0[4], b1[4], b2[4], b3[4];
#pragma unroll
            for (int ni = 0; ni < 4; ++ni) b0[ni] = *(const v8bf*)(bbase + ni * 16 * KDIM);
#pragma unroll
            for (int ni = 0; ni < 4; ++ni) b1[ni] = *(const v8bf*)(bbase + ni * 16 * KDIM + 32);
#pragma unroll
            for (int ni = 0; ni < 4; ++ni) b2[ni] = *(const v8bf*)(bbase + ni * 16 * KDIM + 64);
#pragma unroll
            for (int ni = 0; ni < 4; ++ni) b3[ni] = *(const v8bf*)(bbase + ni * 16 * KDIM + 96);
            // ---- 64 MFMA (ks-major so per-use vmcnt waits pipeline) ----
            __builtin_amdgcn_s_setprio(1);
#pragma unroll
            for (int mi = 0; mi < 4; ++mi)
#pragma unroll
                for (int ni = 0; ni < 4; ++ni)
                    accP[mi][ni] = __builtin_amdgcn_mfma_f32_16x16x32_bf16(
                        areg[mi][0], b0[ni], accP[mi][ni], 0, 0, 0);
#pragma unroll
            for (int mi = 0; mi < 4; ++mi)
#pragma unroll
                for (int ni = 0; ni < 4; ++ni)
                    accP[mi][ni] = __builtin_amdgcn_mfma_f32_16x16x32_bf16(
                        areg[mi][1], b1[ni], accP[mi][ni], 0, 0, 0);
#pragma unroll
            for (int mi = 0; mi < 4; ++mi)
#pragma unroll
                for (int ni = 0; ni < 4; ++ni)
                    accP[mi][ni] = __builtin_amdgcn_mfma_f32_16x16x32_bf16(
                        areg[mi][2], b2[ni], accP[mi][ni], 0, 0, 0);
#pragma unroll
            for (int mi = 0; mi < 4; ++mi)
#pragma unroll
                for (int ni = 0; ni < 4; ++ni)
                    accP[mi][ni] = __builtin_amdgcn_mfma_f32_16x16x32_bf16(
                        areg[mi][3], b3[ni], accP[mi][ni], 0, 0, 0);
            __builtin_amdgcn_s_setprio(0);
            // ---- scale-accumulate P into O, reset P ----
            {
                const int pp = p - pBeg;
                const int jj = MODE ? (pp * 2 + wn) : pp;
                const f32x4* scv = (const f32x4*)(sc + jj * 128);
#pragma unroll
                for (int mi = 0; mi < 4; ++mi) {
                    f32x4 sv = scv[wm * 16 + mi * 4 + lg];
#pragma unroll
                    for (int ni = 0; ni < 4; ++ni) {
                        accO[mi][ni] += sv * accP[mi][ni];
                        accP[mi][ni] = (f32x4){0.f, 0.f, 0.f, 0.f};
                    }
                }
            }
        }
    }
    // ---- epilogue: atomic accumulate ----
#pragma unroll
    for (int mi = 0; mi < 4; ++mi)
#pragma unroll
        for (int ni = 0; ni < 4; ++ni)
#pragma unroll
            for (int r = 0; r < 4; ++r) {
                int row = wm * 64 + mi * 16 + lg * 4 + r;
                int col = MODE ? (ni * 16 + lr)
                               : (halfS * 256 + nh * 128 + wn * 64 + ni * 16 + lr);
                atomicAdd(outAcc + (size_t)(m0 + row) * OUTW + col, accO[mi][ni][r]);
            }
}

extern "C" void kernel_launch(void* const* d_in, const int* in_sizes, int n_in,
                              void* d_out, int out_size, void* d_ws, size_t ws_size,
                              hipStream_t stream) {
    const float* x     = (const float*)d_in[0];
    const float* W_in  = (const float*)d_in[1];
    const float* b_in  = (const float*)d_in[2];
    const float* W_out = (const float*)d_in[3];
    const float* b_out = (const float*)d_in[4];
    float* out = (float*)d_out;

    char* ws = (char*)d_ws;
    unsigned short* hb = (unsigned short*)ws;            // 2 MB  h bf16
    float* ypre        = (float*)(ws + (2u << 20));      // 4 MB
    float* yv          = (float*)(ws + (6u << 20));      // 4 MB  yv = elu(ypre)
    unsigned short* Wb = (unsigned short*)(ws + (10u << 20));  // 68.2 MB bf16 W_out

    k_h<<<(B_N * 512) / 256, 256, 0, stream>>>(x, W_in, b_in, hb);
    k_conv<<<(NROWS_PAD * KDIM / 8) / 256, 256, 0, stream>>>(W_out, Wb);

    // ypre := bias terms (l_in_b bias + real-weighted l_in_w biases)
    k_init_ypre<<<(B_N * 512) / 256, 256, 0, stream>>>(x, b_out, ypre);

    // Stage 2: ypre += sum_i real_i * (h @ W_i^T)  (+ l_in_b panel, scale 1)
    k_pgemm<0><<<512, 256, 0, stream>>>(hb, Wb, x, ypre);

    // yv := elu(ypre)   (computed once — feeds both k_init_out and pgemm<1> scales)
    k_y<<<(B_N * 512) / 256, 256, 0, stream>>>(ypre, yv);

    // out := bias terms (l_out_b bias + yv-weighted l_out_w biases)
    k_init_out<<<(B_N * 64) / 256, 256, 0, stream>>>(yv, b_out, out);

    // Stage 3: out += sum_h' yv_h' * (h @ W2_h'^T)  (+ l_out_b panel, scale 1)
    k_pgemm<1><<<512, 256, 0, stream>>>(hb, Wb, yv, out);
}

// Round 8
// 393.341 us; speedup vs baseline: 1.0654x; 1.0654x over previous
//
#include <hip/hip_runtime.h>
#include <hip/hip_bf16.h>
#include <stdint.h>

// Problem constants
#define B_N   2048
#define XW    128      // x row width (real 64 | meta 64)
#define KDIM  512      // W_out column count (= H)
#define NROWS_W   66112
#define NROWS_PAD 66560   // padded bf16-W rows (MODE1 sub-panels reach exactly 66560)

typedef __bf16 v8bf  __attribute__((ext_vector_type(8)));
typedef float  f32x4 __attribute__((ext_vector_type(4)));

__device__ __forceinline__ unsigned short f2bf(float f) {
    uint32_t u = __float_as_uint(f);
    u += 0x7FFF + ((u >> 16) & 1);          // round-to-nearest-even
    return (unsigned short)(u >> 16);
}
__device__ __forceinline__ float bf2f(unsigned short h) {
    return __uint_as_float(((uint32_t)h) << 16);
}
__device__ __forceinline__ float elu1(float v) {
    return v > 0.0f ? v : expm1f(v);
}
__device__ __forceinline__ void gload_lds16(const void* g, void* l) {
    __builtin_amdgcn_global_load_lds(
        (const __attribute__((address_space(1))) unsigned int*)g,
        (__attribute__((address_space(3))) unsigned int*)l, 16, 0, 0);
}

// ---------------- K1: h = elu(meta @ W_in^T + b_in), stored bf16 ----------------
__global__ void k_h(const float* __restrict__ x, const float* __restrict__ W_in,
                    const float* __restrict__ b_in, unsigned short* __restrict__ hb) {
    int idx = blockIdx.x * 256 + threadIdx.x;      // b*512 + j
    int b = idx >> 9, j = idx & 511;
    const float4* xm = (const float4*)(x + (size_t)b * XW + 64);
    const float4* wr = (const float4*)(W_in + (size_t)j * 64);
    float acc = 0.f;
#pragma unroll
    for (int q = 0; q < 16; ++q) {
        float4 a = xm[q], w = wr[q];
        acc += a.x * w.x + a.y * w.y + a.z * w.z + a.w * w.w;
    }
    acc = elu1(acc + b_in[j]);
    hb[idx] = f2bf(acc);
}

// ---------------- K-conv: W_out f32 -> bf16 (padded rows zeroed) ---------------
__global__ void k_conv(const float* __restrict__ Wf, unsigned short* __restrict__ Wb) {
    size_t c = (size_t)blockIdx.x * 256 + threadIdx.x;  // 8-elem chunk id
    size_t row = c >> 6; int kk = (int)(c & 63);
    union { uint4 v; unsigned short u[8]; } o;
    o.v = (uint4){0, 0, 0, 0};
    if (row < NROWS_W) {
        const float* wp = Wf + row * KDIM + kk * 8;
        float4 w0 = *(const float4*)wp, w1 = *(const float4*)(wp + 4);
        o.u[0] = f2bf(w0.x); o.u[1] = f2bf(w0.y); o.u[2] = f2bf(w0.z); o.u[3] = f2bf(w0.w);
        o.u[4] = f2bf(w1.x); o.u[5] = f2bf(w1.y); o.u[6] = f2bf(w1.z); o.u[7] = f2bf(w1.w);
    }
    *(uint4*)(Wb + c * 8) = o.v;
}

// ---------------- K-init-ypre: ypre = b_out[32768+hh] + sum_i real_i*b_out[i*512+hh]
__global__ void k_init_ypre(const float* __restrict__ x, const float* __restrict__ b_out,
                            float* __restrict__ ypre) {
    int idx = blockIdx.x * 256 + threadIdx.x;   // b*512 + hh
    int b = idx >> 9, hh = idx & 511;
    float acc = b_out[32768 + hh];
    const float* xr = x + (size_t)b * XW;       // real part
#pragma unroll 8
    for (int i = 0; i < 64; ++i)
        acc += xr[i] * b_out[i * 512 + hh];
    ypre[idx] = acc;
}

// ---------------- K-y: yv = elu(ypre)  (elu computed ONCE per element) ---------
__global__ void k_y(const float* __restrict__ ypre, float* __restrict__ yv) {
    int idx = blockIdx.x * 256 + threadIdx.x;
    yv[idx] = elu1(ypre[idx]);
}

// ---------------- K-init-out: out = b_out[66048+o] + sum_hh yv*b_out[33280+hh*64+o]
__global__ void k_init_out(const float* __restrict__ yv, const float* __restrict__ b_out,
                           float* __restrict__ out) {
    int idx = blockIdx.x * 256 + threadIdx.x;   // b*64 + o
    int b = idx >> 6, o = idx & 63;
    float acc = b_out[66048 + o];
    const float* yr = yv + (size_t)b * 512;
#pragma unroll 4
    for (int hh = 0; hh < 512; ++hh)
        acc += yr[hh] * b_out[33280 + hh * 64 + o];
    out[idx] = acc;
}

// ---------------- panel GEMM: 40 static phases, ring-3, 3 blocks/CU ------------
// Sub-panels of 128 W-rows; split = 5 sub-panels (PP=5, 52 splits, exact).
// MODE0: sub-panel (quarter-major) q = quarter*65 + blk; wrow = blk*512+quarter*128;
//        outcol = quarter*128 + c; scale = x[row, blk] (blk=64 -> 1, l_in_b).
// MODE1: q = row-chunk; wrow = 33280 + q*128; outcol = c&63;
//        scale = yv[row, q*2 + (c>>6)] (>=512 -> 1, l_out_b/pad).
// Phases: 8 K-groups (g: K-offset g*64) x 5 sub-panels = 40.
// Per phase: stage t+2 (4 gload_lds), vmcnt(8/4), barrier, 8 ds_read + 32 MFMA
// (frag-major, scale folded immediately -> no persistent accP), barrier.
template<int MODE>
__global__ __launch_bounds__(256, 3)
void k_pgemm(const unsigned short* __restrict__ hb,
             const unsigned short* __restrict__ Wb,
             const float* __restrict__ scaleSrc,
             float* __restrict__ outAcc) {
    constexpr int OUTW = MODE ? 64 : 512;
    constexpr int SCW  = MODE ? 10 : 5;
    constexpr int RST  = MODE ? 128 : 512;   // W-row stride per sub-panel step

    __shared__ char smem[49152 + SCW * 256];
    char* Bs = smem;                              // 3 x [128 rows][128B], swizzled
    unsigned short* scb = (unsigned short*)(smem + 49152);  // bf16 [SCW][128]

    // XCD-pinned: xcd = lid&7 hosts idx [104*xcd, 104*(xcd+1)) = ~6.5 splits.
    const int lid = blockIdx.x;                   // [0,832)
    const int idx = (lid & 7) * 104 + (lid >> 3);
    const int s   = idx >> 4;                     // split 0..51
    const int m0  = (idx & 15) * 128;             // M-tile

    const int quarter = MODE ? 0 : (s / 13);
    const int blkBeg  = MODE ? 0 : ((s % 13) * 5);
    const int rowBase = MODE ? (33280 + s * 5 * 128)
                             : (blkBeg * 512 + quarter * 128);

    const int tid = threadIdx.x;
    const int wid = tid >> 6, l = tid & 63;
    const int lr = l & 15, lg = l >> 4;
    const int wm = wid >> 1, wn = wid & 1;        // wave grid 2x2

    // ---- scales -> LDS (bf16) ----
    for (int c = tid; c < SCW * 128; c += 256) {
        int jj = c >> 7, row = c & 127;
        float v = 1.0f;
        if (MODE == 0) {
            int blk = blkBeg + jj;
            if (blk < 64) v = scaleSrc[(size_t)(m0 + row) * XW + blk];
        } else {
            int gg = (s * 5 + (jj >> 1)) * 2 + (jj & 1);
            if (gg < 512) v = scaleSrc[(size_t)(m0 + row) * KDIM + gg];
        }
        scb[c] = f2bf(v);
    }
    __syncthreads();                              // full drain BEFORE pipeline starts

    const int rsub = tid >> 3;                    // 0..31
    const int sl8  = ((tid & 7) ^ (rsub & 7)) * 8;  // inverse of read swizzle
    const int bXl  = lr & 7;
    int bB[4];
#pragma unroll
    for (int q = 0; q < 4; ++q) bB[q] = (wn * 64 + q * 16 + lr) * 128;

    v8bf areg[4][2];                              // per (K-group) A frags, static idx
    auto loadA = [&](int g2) {
        const unsigned short* ab = hb + (size_t)(m0 + wm * 64 + lr) * KDIM + g2 * 64 + lg * 8;
#pragma unroll
        for (int mi = 0; mi < 4; ++mi)
#pragma unroll
            for (int ks = 0; ks < 2; ++ks)
                areg[mi][ks] = *(const v8bf*)(ab + mi * 16 * KDIM + ks * 32);
    };
    auto stageB = [&](int slot, int g2, int pp2) {
        const unsigned short* src0 = Wb + (size_t)(rowBase + pp2 * RST + rsub) * KDIM
                                   + g2 * 64 + sl8;
        char* dst0 = Bs + slot * 16384 + tid * 16;
#pragma unroll
        for (int qc = 0; qc < 4; ++qc)
            gload_lds16(src0 + (size_t)qc * 32 * KDIM, dst0 + qc * 4096);
    };

    f32x4 accO[4][4];
#pragma unroll
    for (int mi = 0; mi < 4; ++mi)
#pragma unroll
        for (int ni = 0; ni < 4; ++ni) accO[mi][ni] = (f32x4){0.f, 0.f, 0.f, 0.f};

    // prologue: areg group 0, stages 0 and 1
    loadA(0);
    stageB(0, 0, 0);
    stageB(1, 0, 1);
    int slotCur = 0;

    // one phase; pp/vmsel/doStage/doAreg are literals at every call site
    auto phase = [&](int g, int pp, int vmsel, bool doStage, int sg, int sp, bool doAreg) {
        if (doStage) {
            int ss = slotCur + 2; if (ss >= 3) ss -= 3;
            stageB(ss, sg, sp);
        }
        if (vmsel == 0)      asm volatile("s_waitcnt vmcnt(4)" ::: "memory");
        else if (vmsel == 1) asm volatile("s_waitcnt vmcnt(8)" ::: "memory");
        else                 asm volatile("s_waitcnt vmcnt(0)" ::: "memory");
        __builtin_amdgcn_s_barrier();
        const char* Bbuf = Bs + slotCur * 16384;
        v8bf bfr[4][2];
#pragma unroll
        for (int ni = 0; ni < 4; ++ni)
#pragma unroll
            for (int ks = 0; ks < 2; ++ks)
                bfr[ni][ks] = *(const v8bf*)(Bbuf + bB[ni] + (((ks * 4 + lg) ^ bXl) << 4));
        const int jj = MODE ? (pp * 2 + wn) : pp;
        const unsigned short* scp = scb + jj * 128 + wm * 64 + lg * 4;
        __builtin_amdgcn_s_setprio(1);
#pragma unroll
        for (int mi = 0; mi < 4; ++mi) {
            ushort4 su = *(const ushort4*)(scp + mi * 16);
            f32x4 sv = {bf2f(su.x), bf2f(su.y), bf2f(su.z), bf2f(su.w)};
#pragma unroll
            for (int ni = 0; ni < 4; ++ni) {
                f32x4 t0 = __builtin_amdgcn_mfma_f32_16x16x32_bf16(
                    areg[mi][0], bfr[ni][0], (f32x4){0.f, 0.f, 0.f, 0.f}, 0, 0, 0);
                t0 = __builtin_amdgcn_mfma_f32_16x16x32_bf16(
                    areg[mi][1], bfr[ni][1], t0, 0, 0, 0);
                accO[mi][ni] += sv * t0;
            }
        }
        __builtin_amdgcn_s_setprio(0);
        if (doAreg) loadA(g + 1);                 // after last areg use; hides under tail
        __builtin_amdgcn_s_barrier();
        slotCur = slotCur + 1; if (slotCur == 3) slotCur = 0;
    };

    for (int g = 0; g < 7; ++g) {
        phase(g, 0, 0, true, g, 2, false);        // group start: drain areg + s(t)
        phase(g, 1, 1, true, g, 3, false);
        phase(g, 2, 1, true, g, 4, false);
        phase(g, 3, 1, true, g + 1, 0, false);
        phase(g, 4, 1, true, g + 1, 1, true);     // reload areg for g+1
    }
    // peeled last group (static vmcnt tail)
    phase(7, 0, 0, true,  7, 2, false);
    phase(7, 1, 1, true,  7, 3, false);
    phase(7, 2, 1, true,  7, 4, false);
    phase(7, 3, 0, false, 0, 0, false);
    phase(7, 4, 2, false, 0, 0, false);

    // ---- epilogue: atomic accumulate ----
#pragma unroll
    for (int mi = 0; mi < 4; ++mi)
#pragma unroll
        for (int ni = 0; ni < 4; ++ni)
#pragma unroll
            for (int r = 0; r < 4; ++r) {
                int row = wm * 64 + mi * 16 + lg * 4 + r;
                int col = MODE ? (ni * 16 + lr)
                               : (quarter * 128 + wn * 64 + ni * 16 + lr);
                atomicAdd(outAcc + (size_t)(m0 + row) * OUTW + col, accO[mi][ni][r]);
            }
}

extern "C" void kernel_launch(void* const* d_in, const int* in_sizes, int n_in,
                              void* d_out, int out_size, void* d_ws, size_t ws_size,
                              hipStream_t stream) {
    const float* x     = (const float*)d_in[0];
    const float* W_in  = (const float*)d_in[1];
    const float* b_in  = (const float*)d_in[2];
    const float* W_out = (const float*)d_in[3];
    const float* b_out = (const float*)d_in[4];
    float* out = (float*)d_out;

    char* ws = (char*)d_ws;
    unsigned short* hb = (unsigned short*)ws;            // 2 MB  h bf16
    float* ypre        = (float*)(ws + (2u << 20));      // 4 MB
    float* yv          = (float*)(ws + (6u << 20));      // 4 MB  yv = elu(ypre)
    unsigned short* Wb = (unsigned short*)(ws + (10u << 20));  // 68.2 MB bf16 W_out

    k_h<<<(B_N * 512) / 256, 256, 0, stream>>>(x, W_in, b_in, hb);
    k_conv<<<((size_t)NROWS_PAD * KDIM / 8) / 256, 256, 0, stream>>>(W_out, Wb);

    // ypre := bias terms (l_in_b bias + real-weighted l_in_w biases)
    k_init_ypre<<<(B_N * 512) / 256, 256, 0, stream>>>(x, b_out, ypre);

    // Stage 2: ypre += sum_i real_i * (h @ W_i^T)  (+ l_in_b panel, scale 1)
    k_pgemm<0><<<832, 256, 0, stream>>>(hb, Wb, x, ypre);

    // yv := elu(ypre)
    k_y<<<(B_N * 512) / 256, 256, 0, stream>>>(ypre, yv);

    // out := bias terms (l_out_b bias + yv-weighted l_out_w biases)
    k_init_out<<<(B_N * 64) / 256, 256, 0, stream>>>(yv, b_out, out);

    // Stage 3: out += sum_h' yv_h' * (h @ W2_h'^T)  (+ l_out_b panel, scale 1)
    k_pgemm<1><<<832, 256, 0, stream>>>(hb, Wb, yv, out);
}